// Round 1
// baseline (367.317 us; speedup 1.0000x reference)
//
#include <hip/hip_runtime.h>
#include <math.h>

#define NB 8192
#define T 65
#define Q 20
#define D 100
#define SP 21   // sS pitch (gcd(21,32)=1 -> conflict-free row access)

__global__ __launch_bounds__(256) void attn_fused_kernel(
    const float* __restrict__ Hg,   // [B,T,D]
    const float* __restrict__ Ug,   // [B,Q,D]
    const float* __restrict__ Ws1,  // [T,D] (tiled single row)
    const float* __restrict__ Ws2,  // [Q,D]
    const float* __restrict__ Ws3,  // [T,D]
    float* __restrict__ Gg)         // [B,T,4D]
{
    __shared__ float sH[T*D];      // 26000 B
    __shared__ float sU[Q*D];      //  8000 B
    __shared__ float sU3[Q*D];     //  8000 B  (U * w3)
    __shared__ float sS[T*SP];     //  5460 B  (scores, then at in-place)
    __shared__ float sW1[D];
    __shared__ float sW2[D];
    __shared__ float sH1[T];
    __shared__ float sU1q[Q];
    __shared__ float sBeta[T];
    __shared__ float sBsm[T];
    __shared__ float sHtil[D];

    const int b   = blockIdx.x;
    const int tid = threadIdx.x;
    const float* Hb = Hg + (size_t)b * (T*D);
    const float* Ub = Ug + (size_t)b * (Q*D);

    // ---- Phase 1: stage H, U, w1, w2 ----
    {
        const float4* src = reinterpret_cast<const float4*>(Hb);  // 6500 = 1625*4, 16B aligned
        float4* dst = reinterpret_cast<float4*>(sH);
        for (int i = tid; i < (T*D)/4; i += 256) dst[i] = src[i];
    }
    {
        const float4* src = reinterpret_cast<const float4*>(Ub);  // 2000 = 500*4
        float4* dst = reinterpret_cast<float4*>(sU);
        for (int i = tid; i < (Q*D)/4; i += 256) dst[i] = src[i];
    }
    if (tid < D) {
        sW1[tid] = Ws1[tid];   // rows of Ws* are identical by construction (tiled row 0)
        sW2[tid] = Ws2[tid];
    }
    __syncthreads();

    // ---- Phase 2: U3 = U * w3 ; h1[t] = H[t]·w1 ; U1[q] = U[q]·w2 ----
    for (int i = tid; i < Q*D; i += 256) {
        sU3[i] = sU[i] * Ws3[i % D];   // Ws3 row 0, L2-resident broadcast
    }
    if (tid < T) {
        const float4* hr = reinterpret_cast<const float4*>(sH + tid*D);
        const float4* wr = reinterpret_cast<const float4*>(sW1);
        float acc = 0.f;
        #pragma unroll
        for (int k = 0; k < D/4; ++k) {
            const float4 h = hr[k], w = wr[k];
            acc = fmaf(h.x, w.x, acc); acc = fmaf(h.y, w.y, acc);
            acc = fmaf(h.z, w.z, acc); acc = fmaf(h.w, w.w, acc);
        }
        sH1[tid] = acc;
    } else if (tid >= 128 && tid < 128 + Q) {
        const int q = tid - 128;
        const float4* ur = reinterpret_cast<const float4*>(sU + q*D);
        const float4* wr = reinterpret_cast<const float4*>(sW2);
        float acc = 0.f;
        #pragma unroll
        for (int k = 0; k < D/4; ++k) {
            const float4 u = ur[k], w = wr[k];
            acc = fmaf(u.x, w.x, acc); acc = fmaf(u.y, w.y, acc);
            acc = fmaf(u.z, w.z, acc); acc = fmaf(u.w, w.w, acc);
        }
        sU1q[q] = acc;
    }
    __syncthreads();

    // ---- Phase 3: S'[t,q] = U1[q] + H[t]·U3[q]  (65x20 GEMM, reg-tiled 1x5) ----
    for (int p = tid; p < T*4; p += 256) {       // 260 work units; threads 0..3 also do t=64
        const int t = p >> 2;
        const int j = p & 3;                      // q-group of 5
        float acc[5];
        #pragma unroll
        for (int k = 0; k < 5; ++k) acc[k] = sU1q[j*5 + k];
        const float4* hr = reinterpret_cast<const float4*>(sH + t*D);
        #pragma unroll 5
        for (int d4 = 0; d4 < D/4; ++d4) {
            const float4 h = hr[d4];
            #pragma unroll
            for (int k = 0; k < 5; ++k) {
                const float4 u = reinterpret_cast<const float4*>(sU3 + (j*5 + k)*D)[d4];
                acc[k] = fmaf(h.x, u.x, acc[k]);
                acc[k] = fmaf(h.y, u.y, acc[k]);
                acc[k] = fmaf(h.z, u.z, acc[k]);
                acc[k] = fmaf(h.w, u.w, acc[k]);
            }
        }
        #pragma unroll
        for (int k = 0; k < 5; ++k) sS[t*SP + j*5 + k] = acc[k];
    }
    __syncthreads();

    // ---- Phase 4: softmax over q (in place -> at), beta[t] = h1[t] + max_q S' ----
    if (tid < T) {
        float row[Q];
        float m = -1e30f;
        #pragma unroll
        for (int q = 0; q < Q; ++q) { row[q] = sS[tid*SP + q]; m = fmaxf(m, row[q]); }
        float s = 0.f;
        #pragma unroll
        for (int q = 0; q < Q; ++q) { row[q] = __expf(row[q] - m); s += row[q]; }
        const float inv = 1.f / s;
        #pragma unroll
        for (int q = 0; q < Q; ++q) sS[tid*SP + q] = row[q] * inv;
        sBeta[tid] = sH1[tid] + m;
    }
    __syncthreads();

    // ---- Phase 5: softmax over t of beta (wave 0; lane 0 also owns t=64) ----
    if (tid < 64) {
        const float v0 = sBeta[tid];
        const float v1 = (tid == 0) ? sBeta[64] : -1e30f;
        float mx = fmaxf(v0, v1);
        #pragma unroll
        for (int off = 32; off >= 1; off >>= 1)
            mx = fmaxf(mx, __shfl_xor(mx, off, 64));
        const float e0 = __expf(v0 - mx);
        const float e1 = (tid == 0) ? __expf(v1 - mx) : 0.f;
        float s = e0 + e1;
        #pragma unroll
        for (int off = 32; off >= 1; off >>= 1)
            s += __shfl_xor(s, off, 64);
        const float inv = 1.f / s;
        sBsm[tid] = e0 * inv;
        if (tid == 0) sBsm[64] = e1 * inv;
    }
    __syncthreads();

    // ---- Phase 6: Htil[d] = sum_t b[t]*H[t,d] ----
    if (tid < D) {
        float acc = 0.f;
        #pragma unroll 5
        for (int t = 0; t < T; ++t)
            acc = fmaf(sBsm[t], sH[t*D + tid], acc);
        sHtil[tid] = acc;
    }
    __syncthreads();

    // ---- Phase 7: output G[b,t,:] = [H | Util | H*Util | H*Htil] ----
    {
        const int wv   = tid >> 6;
        const int lane = tid & 63;
        float* Gb = Gg + (size_t)b * (T*4*D);
        for (int t = wv; t < T; t += 4) {
            float at[Q];
            #pragma unroll
            for (int q = 0; q < Q; ++q) at[q] = sS[t*SP + q];   // wave-broadcast reads
            float* Gr = Gb + t*4*D;
            #pragma unroll
            for (int half = 0; half < 2; ++half) {
                const int d = lane + 64*half;
                if (d < D) {
                    float util = 0.f;
                    #pragma unroll
                    for (int q = 0; q < Q; ++q)
                        util = fmaf(at[q], sU[q*D + d], util);
                    const float h    = sH[t*D + d];
                    const float htil = sHtil[d];
                    Gr[d]         = h;
                    Gr[D + d]     = util;
                    Gr[2*D + d]   = h * util;
                    Gr[3*D + d]   = h * htil;
                }
            }
        }
    }
}

extern "C" void kernel_launch(void* const* d_in, const int* in_sizes, int n_in,
                              void* d_out, int out_size, void* d_ws, size_t ws_size,
                              hipStream_t stream) {
    const float* H   = (const float*)d_in[0];
    const float* U   = (const float*)d_in[1];
    const float* Ws1 = (const float*)d_in[2];
    const float* Ws2 = (const float*)d_in[3];
    const float* Ws3 = (const float*)d_in[4];
    float* G = (float*)d_out;
    hipLaunchKernelGGL(attn_fused_kernel, dim3(NB), dim3(256), 0, stream,
                       H, U, Ws1, Ws2, Ws3, G);
}

// Round 2
// 320.844 us; speedup vs baseline: 1.1448x; 1.1448x over previous
//
#include <hip/hip_runtime.h>
#include <math.h>

#define NB 8192
#define T 65
#define Q 20
#define D 100
#define D4 25          // D/4
#define C 21           // S-GEMM columns = Q + 1 (h1 folded in as col 20)
#define SP 24          // sS row pitch in floats (16B-aligned rows)

__global__ __launch_bounds__(256) void attn_fused_kernel(
    const float* __restrict__ Hg,   // [B,T,D]
    const float* __restrict__ Ug,   // [B,Q,D]
    const float* __restrict__ Ws1,  // [T,D] (tiled single row)
    const float* __restrict__ Ws2,  // [Q,D]
    const float* __restrict__ Ws3,  // [T,D]
    float* __restrict__ Gg)         // [B,T,4D]
{
    __shared__ __align__(16) float sH[T*D];      // 26000 B
    __shared__ __align__(16) float sU[Q*D];      //  8000 B
    __shared__ __align__(16) float sU3e[C*D];    //  8400 B: rows 0..19 = U*w3, row 20 = w1
    __shared__ __align__(16) float sS[T*SP];     //  6240 B
    __shared__ __align__(16) float sHtil[D];
    __shared__ float sU1q[Q];
    __shared__ float sBeta[T];
    __shared__ float sBsm[T];

    const int b   = blockIdx.x;
    const int tid = threadIdx.x;
    const float* Hb = Hg + (size_t)b * (T*D);
    const float* Ub = Ug + (size_t)b * (Q*D);
    float4* sH4   = (float4*)sH;
    float4* sU4   = (float4*)sU;
    float4* sU3e4 = (float4*)sU3e;
    float4* sS4   = (float4*)sS;

    // ---- P1: stage H, U (coalesced float4) ----
    {
        const float4* hs = (const float4*)Hb;
        for (int i = tid; i < T*D4; i += 256) sH4[i] = hs[i];
        const float4* us = (const float4*)Ub;
        for (int i = tid; i < Q*D4; i += 256) sU4[i] = us[i];
    }
    __syncthreads();

    // ---- P2: build U3e (U*w3 rows + w1 row), U1[q] ----
    {
        const float4* w3g = (const float4*)Ws3;   // row 0 (all rows identical)
        const float4* w1g = (const float4*)Ws1;
        for (int i = tid; i < C*D4; i += 256) {
            const int r  = i / D4;
            const int dd = i - r*D4;
            float4 v;
            if (r < Q) {
                const float4 u = sU4[i];          // [r][dd], same pitch
                const float4 w = w3g[dd];
                v.x = u.x*w.x; v.y = u.y*w.y; v.z = u.z*w.z; v.w = u.w*w.w;
            } else {
                v = w1g[dd];
            }
            sU3e4[i] = v;
        }
        if (tid < Q) {
            const float4* ur = sU4 + tid*D4;
            const float4* w2 = (const float4*)Ws2;
            float acc = 0.f;
            #pragma unroll
            for (int k = 0; k < D4; ++k) {
                const float4 u = ur[k], w = w2[k];
                acc = fmaf(u.x, w.x, acc); acc = fmaf(u.y, w.y, acc);
                acc = fmaf(u.z, w.z, acc); acc = fmaf(u.w, w.w, acc);
            }
            sU1q[tid] = acc;
        }
    }
    __syncthreads();

    // ---- P3: S'[t,c] = H[t]·U3e[c]  (65x21 GEMM, reg tile 4t x 3c) ----
    if (tid < 119) {
        const int tg = tid / 7;          // 0..16
        const int jg = tid - tg*7;       // 0..6
        const int t0 = tg*4;
        float acc[4][3];
        #pragma unroll
        for (int i = 0; i < 4; ++i)
            #pragma unroll
            for (int k = 0; k < 3; ++k) acc[i][k] = 0.f;
        #pragma unroll 5
        for (int d4 = 0; d4 < D4; ++d4) {
            float4 h[4];
            #pragma unroll
            for (int i = 0; i < 4; ++i) h[i] = sH4[(t0+i)*D4 + d4];  // tg=16 over-reads into sU: unused
            #pragma unroll
            for (int k = 0; k < 3; ++k) {
                const float4 w = sU3e4[(jg*3+k)*D4 + d4];
                #pragma unroll
                for (int i = 0; i < 4; ++i) {
                    acc[i][k] = fmaf(h[i].x, w.x, acc[i][k]);
                    acc[i][k] = fmaf(h[i].y, w.y, acc[i][k]);
                    acc[i][k] = fmaf(h[i].z, w.z, acc[i][k]);
                    acc[i][k] = fmaf(h[i].w, w.w, acc[i][k]);
                }
            }
        }
        #pragma unroll
        for (int i = 0; i < 4; ++i) {
            const int t = t0 + i;
            if (t < T) {
                #pragma unroll
                for (int k = 0; k < 3; ++k) {
                    const int cc = jg*3 + k;
                    const float add = (cc < Q) ? sU1q[cc] : 0.f;
                    sS[t*SP + cc] = acc[i][k] + add;
                }
            }
        }
    }
    __syncthreads();

    // ---- P4: softmax over q (in place), beta[t] = h1[t] + max_q ----
    if (tid < T) {
        const int t = tid;
        float4 r[5];
        #pragma unroll
        for (int c = 0; c < 5; ++c) r[c] = sS4[t*6 + c];
        const float h1t = sS[t*SP + 20];
        float m = r[0].x;
        #pragma unroll
        for (int c = 0; c < 5; ++c) {
            m = fmaxf(m, fmaxf(fmaxf(r[c].x, r[c].y), fmaxf(r[c].z, r[c].w)));
        }
        float s = 0.f;
        #pragma unroll
        for (int c = 0; c < 5; ++c) {
            r[c].x = __expf(r[c].x - m); r[c].y = __expf(r[c].y - m);
            r[c].z = __expf(r[c].z - m); r[c].w = __expf(r[c].w - m);
            s += r[c].x + r[c].y + r[c].z + r[c].w;
        }
        const float inv = 1.f / s;
        #pragma unroll
        for (int c = 0; c < 5; ++c) {
            r[c].x *= inv; r[c].y *= inv; r[c].z *= inv; r[c].w *= inv;
            sS4[t*6 + c] = r[c];
        }
        sBeta[t] = h1t + m;
    }
    __syncthreads();

    // ---- P5: softmax over t of beta (wave 0) ----
    if (tid < 64) {
        const float v0 = sBeta[tid];
        const float v1 = (tid == 0) ? sBeta[64] : -1e30f;
        float mx = fmaxf(v0, v1);
        #pragma unroll
        for (int off = 32; off >= 1; off >>= 1)
            mx = fmaxf(mx, __shfl_xor(mx, off, 64));
        const float e0 = __expf(v0 - mx);
        const float e1 = (tid == 0) ? __expf(v1 - mx) : 0.f;
        float s = e0 + e1;
        #pragma unroll
        for (int off = 32; off >= 1; off >>= 1)
            s += __shfl_xor(s, off, 64);
        const float inv = 1.f / s;
        sBsm[tid] = e0 * inv;
        if (tid == 0) sBsm[64] = e1 * inv;
    }
    __syncthreads();

    // ---- P6: Htil[d] = sum_t b[t]*H[t,d]  (25 lanes, float4) ----
    if (tid < D4) {
        float4 acc = {0.f, 0.f, 0.f, 0.f};
        #pragma unroll 5
        for (int t = 0; t < T; ++t) {
            const float bt = sBsm[t];
            const float4 h = sH4[t*D4 + tid];
            acc.x = fmaf(bt, h.x, acc.x); acc.y = fmaf(bt, h.y, acc.y);
            acc.z = fmaf(bt, h.z, acc.z); acc.w = fmaf(bt, h.w, acc.w);
        }
        ((float4*)sHtil)[tid] = acc;
    }
    __syncthreads();

    // ---- P7: output. t-pairs, 50 lanes = 2t x 25 d-groups, all float4 ----
    {
        const int wv   = tid >> 6;
        const int lane = tid & 63;
        const int tsel = lane / 25;          // 0,1 valid; 2 -> idle
        const int g    = lane - tsel*25;     // 0..24 (lanes>=50: some 0..13, unused)
        const bool act = (lane < 50);
        float* Gb = Gg + (size_t)b * (T*4*D);
        const float4 htil4 = ((float4*)sHtil)[g];
        const float4* ug = sU4 + g;          // + q*D4 per row

        for (int pr = wv; pr < 33; pr += 4) {
            const int t   = pr*2 + tsel;
            const bool val = act && (t < T);
            const int tr  = val ? t : 0;

            float4 a0 = sS4[tr*6 + 0];
            float4 a1 = sS4[tr*6 + 1];
            float4 a2 = sS4[tr*6 + 2];
            float4 a3 = sS4[tr*6 + 3];
            float4 a4 = sS4[tr*6 + 4];

            float4 acc = {0.f, 0.f, 0.f, 0.f};
            #define QSTEP(av, comp, qq) { \
                const float4 u = ug[(qq)*D4]; \
                acc.x = fmaf(av.comp, u.x, acc.x); \
                acc.y = fmaf(av.comp, u.y, acc.y); \
                acc.z = fmaf(av.comp, u.z, acc.z); \
                acc.w = fmaf(av.comp, u.w, acc.w); }
            QSTEP(a0,x,0)  QSTEP(a0,y,1)  QSTEP(a0,z,2)  QSTEP(a0,w,3)
            QSTEP(a1,x,4)  QSTEP(a1,y,5)  QSTEP(a1,z,6)  QSTEP(a1,w,7)
            QSTEP(a2,x,8)  QSTEP(a2,y,9)  QSTEP(a2,z,10) QSTEP(a2,w,11)
            QSTEP(a3,x,12) QSTEP(a3,y,13) QSTEP(a3,z,14) QSTEP(a3,w,15)
            QSTEP(a4,x,16) QSTEP(a4,y,17) QSTEP(a4,z,18) QSTEP(a4,w,19)
            #undef QSTEP

            const float4 h4 = sH4[tr*D4 + g];
            if (val) {
                float* base = Gb + (size_t)t*(4*D);
                float4 hu, hh;
                hu.x = h4.x*acc.x;   hu.y = h4.y*acc.y;   hu.z = h4.z*acc.z;   hu.w = h4.w*acc.w;
                hh.x = h4.x*htil4.x; hh.y = h4.y*htil4.y; hh.z = h4.z*htil4.z; hh.w = h4.w*htil4.w;
                ((float4*)(base        ))[g] = h4;
                ((float4*)(base +   D  ))[g] = acc;
                ((float4*)(base + 2*D  ))[g] = hu;
                ((float4*)(base + 3*D  ))[g] = hh;
            }
        }
    }
}

extern "C" void kernel_launch(void* const* d_in, const int* in_sizes, int n_in,
                              void* d_out, int out_size, void* d_ws, size_t ws_size,
                              hipStream_t stream) {
    const float* H   = (const float*)d_in[0];
    const float* U   = (const float*)d_in[1];
    const float* Ws1 = (const float*)d_in[2];
    const float* Ws2 = (const float*)d_in[3];
    const float* Ws3 = (const float*)d_in[4];
    float* G = (float*)d_out;
    hipLaunchKernelGGL(attn_fused_kernel, dim3(NB), dim3(256), 0, stream,
                       H, U, Ws1, Ws2, Ws3, G);
}